// Round 1
// baseline (270.133 us; speedup 1.0000x reference)
//
#include <hip/hip_runtime.h>
#include <float.h>
#include <math.h>

#define B 128
#define D 128
#define N 3072      // 3*32*32
#define NP 4096     // next pow2 for bitonic sort

// K1: row-wise L2 normalize of z [B,D]
__global__ void normalize_z(const float* __restrict__ z, float* __restrict__ zn) {
    int row = blockIdx.x;
    int t = threadIdx.x;               // 128 threads
    float v = z[row * D + t];
    float s = v * v;
    #pragma unroll
    for (int o = 32; o > 0; o >>= 1) s += __shfl_down(s, o, 64);
    __shared__ float red[2];
    if ((t & 63) == 0) red[t >> 6] = s;
    __syncthreads();
    float norm = sqrtf(red[0] + red[1]);
    norm = fmaxf(norm, 1e-12f);
    zn[row * D + t] = v / norm;
}

// K2: z_cos[i][j] = dot(zn[i], zn[j])  — tiny (4 MFLOP), cache-fed
__global__ void zcos_kernel(const float* __restrict__ zn, float* __restrict__ zcos) {
    int i = blockIdx.x;
    int j = threadIdx.x;               // 128 threads
    __shared__ float ri[D];
    ri[j] = zn[i * D + j];
    __syncthreads();
    const float* rj = zn + j * D;
    float s = 0.f;
    #pragma unroll 8
    for (int k = 0; k < D; k++) s += ri[k] * rj[k];
    zcos[i * D + j] = s;
}

// K3: global max over z_cos (16384 values), single block
__global__ void max_kernel(const float* __restrict__ zcos, float* __restrict__ maxv) {
    float m = -FLT_MAX;
    for (int idx = threadIdx.x; idx < B * B; idx += blockDim.x) m = fmaxf(m, zcos[idx]);
    #pragma unroll
    for (int o = 32; o > 0; o >>= 1) m = fmaxf(m, __shfl_down(m, o, 64));
    __shared__ float red[4];
    if ((threadIdx.x & 63) == 0) red[threadIdx.x >> 6] = m;
    __syncthreads();
    if (threadIdx.x == 0)
        *maxv = fmaxf(fmaxf(red[0], red[1]), fmaxf(red[2], red[3]));
}

// K4: bitonic sort each row of x (N=3072 padded to NP=4096 with +FLT_MAX) in LDS
__global__ void sort_rows(const float* __restrict__ x, float* __restrict__ xs) {
    __shared__ float buf[NP];          // 16 KB
    int row = blockIdx.x;
    const float* xr = x + (size_t)row * N;
    for (int i = threadIdx.x; i < NP; i += blockDim.x)
        buf[i] = (i < N) ? xr[i] : FLT_MAX;
    __syncthreads();
    for (int k = 2; k <= NP; k <<= 1) {
        for (int j = k >> 1; j > 0; j >>= 1) {
            for (int i = threadIdx.x; i < NP; i += blockDim.x) {
                int ixj = i ^ j;
                if (ixj > i) {
                    float a = buf[i], b = buf[ixj];
                    if ((i & k) == 0) {
                        if (a > b) { buf[i] = b; buf[ixj] = a; }
                    } else {
                        if (a < b) { buf[i] = b; buf[ixj] = a; }
                    }
                }
            }
            __syncthreads();
        }
    }
    for (int i = threadIdx.x; i < N; i += blockDim.x)
        xs[(size_t)row * N + i] = buf[i];
}

// K5: one block per (i,j) pair: EMD + (emd - cosd)^2 -> pair_out
__global__ void pair_kernel(const float* __restrict__ xs, const float* __restrict__ zcos,
                            const float* __restrict__ maxv, float* __restrict__ pair_out) {
    int bid = blockIdx.x;
    int i = bid >> 7, j = bid & (B - 1);
    const float4* a = (const float4*)(xs + (size_t)i * N);
    const float4* b = (const float4*)(xs + (size_t)j * N);
    float s = 0.f;
    for (int t = threadIdx.x; t < N / 4; t += blockDim.x) {
        float4 va = a[t], vb = b[t];
        s += fabsf(va.x - vb.x) + fabsf(va.y - vb.y)
           + fabsf(va.z - vb.z) + fabsf(va.w - vb.w);
    }
    #pragma unroll
    for (int o = 32; o > 0; o >>= 1) s += __shfl_down(s, o, 64);
    __shared__ float red[4];
    if ((threadIdx.x & 63) == 0) red[threadIdx.x >> 6] = s;
    __syncthreads();
    if (threadIdx.x == 0) {
        float emd = (red[0] + red[1] + red[2] + red[3]) * (1.0f / N);
        float cosd = *maxv - zcos[bid];
        float d = emd - cosd;
        pair_out[bid] = d * d;
    }
}

// K6: mean over 16384 pair values -> out[0]
__global__ void final_kernel(const float* __restrict__ pair_out, float* __restrict__ out) {
    float s = 0.f;
    for (int idx = threadIdx.x; idx < B * B; idx += blockDim.x) s += pair_out[idx];
    #pragma unroll
    for (int o = 32; o > 0; o >>= 1) s += __shfl_down(s, o, 64);
    __shared__ float red[4];
    if ((threadIdx.x & 63) == 0) red[threadIdx.x >> 6] = s;
    __syncthreads();
    if (threadIdx.x == 0)
        out[0] = (red[0] + red[1] + red[2] + red[3]) * (1.0f / (B * B));
}

extern "C" void kernel_launch(void* const* d_in, const int* in_sizes, int n_in,
                              void* d_out, int out_size, void* d_ws, size_t ws_size,
                              hipStream_t stream) {
    const float* z = (const float*)d_in[0];   // [128,128]
    const float* x = (const float*)d_in[1];   // [128,3,32,32]
    float* out = (float*)d_out;               // [1]
    float* ws = (float*)d_ws;

    float* zn   = ws;                         // 16384 floats
    float* zcos = ws + 16384;                 // 16384 floats
    float* maxv = ws + 32768;                 // 1 float (+63 pad)
    float* pair = ws + 32832;                 // 16384 floats
    float* xs   = ws + 32832 + 16384;         // 393216 floats

    normalize_z<<<B, D, 0, stream>>>(z, zn);
    zcos_kernel<<<B, D, 0, stream>>>(zn, zcos);
    max_kernel<<<1, 256, 0, stream>>>(zcos, maxv);
    sort_rows<<<B, 256, 0, stream>>>(x, xs);
    pair_kernel<<<B * B, 256, 0, stream>>>(xs, zcos, maxv, pair);
    final_kernel<<<1, 256, 0, stream>>>(pair, out);
}

// Round 2
// 123.496 us; speedup vs baseline: 2.1874x; 2.1874x over previous
//
#include <hip/hip_runtime.h>
#include <float.h>
#include <math.h>

#define B 128
#define D 128
#define N 3072      // 3*32*32
#define NP 4096     // next pow2 for bitonic sort
#define NPAIR (B*(B+1)/2)   // 8256 upper-triangular pairs (i<=j)

// K1: row-wise L2 normalize of z [B,D]
__global__ void normalize_z(const float* __restrict__ z, float* __restrict__ zn) {
    int row = blockIdx.x;
    int t = threadIdx.x;               // 128 threads
    float v = z[row * D + t];
    float s = v * v;
    #pragma unroll
    for (int o = 32; o > 0; o >>= 1) s += __shfl_down(s, o, 64);
    __shared__ float red[2];
    if ((t & 63) == 0) red[t >> 6] = s;
    __syncthreads();
    float norm = sqrtf(red[0] + red[1]);
    norm = fmaxf(norm, 1e-12f);
    zn[row * D + t] = v / norm;
}

// K2: z_cos[i][j] = dot(zn[i], zn[j])  — tiny (4 MFLOP), cache-fed
__global__ void zcos_kernel(const float* __restrict__ zn, float* __restrict__ zcos) {
    int i = blockIdx.x;
    int j = threadIdx.x;               // 128 threads
    __shared__ float ri[D];
    ri[j] = zn[i * D + j];
    __syncthreads();
    const float* rj = zn + j * D;
    float s = 0.f;
    #pragma unroll 8
    for (int k = 0; k < D; k++) s += ri[k] * rj[k];
    zcos[i * D + j] = s;
}

// K3: global max over z_cos (16384 values), single block
__global__ void max_kernel(const float* __restrict__ zcos, float* __restrict__ maxv) {
    float m = -FLT_MAX;
    for (int idx = threadIdx.x; idx < B * B; idx += blockDim.x) m = fmaxf(m, zcos[idx]);
    #pragma unroll
    for (int o = 32; o > 0; o >>= 1) m = fmaxf(m, __shfl_down(m, o, 64));
    __shared__ float red[4];
    if ((threadIdx.x & 63) == 0) red[threadIdx.x >> 6] = m;
    __syncthreads();
    if (threadIdx.x == 0)
        *maxv = fmaxf(fmaxf(red[0], red[1]), fmaxf(red[2], red[3]));
}

// K4: bitonic sort each row of x (N=3072 padded to NP=4096 with +FLT_MAX) in LDS.
// 1024 threads; pair-index formulation: each thread does exactly 2
// compare-exchanges per pass (2048 pairs total), no wasted iterations.
__global__ __launch_bounds__(1024) void sort_rows(const float* __restrict__ x,
                                                  float* __restrict__ xs) {
    __shared__ float buf[NP];          // 16 KB
    int row = blockIdx.x;
    int tid = threadIdx.x;

    // load 3072 floats via float4 (768 threads), pad tail to FLT_MAX
    const float4* xr = (const float4*)(x + (size_t)row * N);
    if (tid < N / 4)
        ((float4*)buf)[tid] = xr[tid];
    else
        ((float4*)buf)[tid] = make_float4(FLT_MAX, FLT_MAX, FLT_MAX, FLT_MAX);
    __syncthreads();

    for (int k = 2; k <= NP; k <<= 1) {
        for (int j = k >> 1; j > 0; j >>= 1) {
            #pragma unroll
            for (int u = 0; u < 2; u++) {
                int p = tid + u * 1024;            // pair index in [0, 2048)
                int i = ((p & ~(j - 1)) << 1) | (p & (j - 1));
                int pj = i | j;
                float a = buf[i];
                float b = buf[pj];
                bool up = ((i & k) == 0);
                if ((a > b) == up) { buf[i] = b; buf[pj] = a; }
            }
            __syncthreads();
        }
    }

    if (tid < N / 4)
        ((float4*)(xs + (size_t)row * N))[tid] = ((float4*)buf)[tid];
}

// K5: one WAVE per upper-triangular pair (i<=j): EMD + weighted squared error.
// EMD/cosd are symmetric -> weight 2 off-diagonal, 1 on diagonal.
__global__ __launch_bounds__(64) void pair_kernel(const float* __restrict__ xs,
                                                  const float* __restrict__ zcos,
                                                  const float* __restrict__ maxv,
                                                  float* __restrict__ pair_out) {
    int t = blockIdx.x;                // triangular index
    // decode t -> (i, j), i<=j ; start(i) = i*B - i*(i-1)/2
    float ff = (float)(2 * B + 1);
    int i = (int)((ff - sqrtf(ff * ff - 8.0f * (float)t)) * 0.5f);
    if (i < 0) i = 0;
    if (i > B - 1) i = B - 1;
    while ((i + 1) * B - ((i + 1) * i) / 2 <= t) i++;
    while (i * B - (i * (i - 1)) / 2 > t) i--;
    int j = i + (t - (i * B - (i * (i - 1)) / 2));

    const float4* a = (const float4*)(xs + (size_t)i * N);
    const float4* b = (const float4*)(xs + (size_t)j * N);
    float s = 0.f;
    #pragma unroll
    for (int u = 0; u < N / 4 / 64; u++) {         // 12 iterations
        int idx = threadIdx.x + u * 64;
        float4 va = a[idx], vb = b[idx];
        s += fabsf(va.x - vb.x) + fabsf(va.y - vb.y)
           + fabsf(va.z - vb.z) + fabsf(va.w - vb.w);
    }
    #pragma unroll
    for (int o = 32; o > 0; o >>= 1) s += __shfl_down(s, o, 64);
    if (threadIdx.x == 0) {
        float emd = s * (1.0f / N);
        float cosd = *maxv - zcos[i * B + j];
        float d = emd - cosd;
        float w = (i == j) ? 1.0f : 2.0f;
        pair_out[t] = w * d * d;
    }
}

// K6: sum over 8256 weighted pair values, /(B*B) -> out[0]
__global__ void final_kernel(const float* __restrict__ pair_out, float* __restrict__ out) {
    float s = 0.f;
    for (int idx = threadIdx.x; idx < NPAIR; idx += blockDim.x) s += pair_out[idx];
    #pragma unroll
    for (int o = 32; o > 0; o >>= 1) s += __shfl_down(s, o, 64);
    __shared__ float red[4];
    if ((threadIdx.x & 63) == 0) red[threadIdx.x >> 6] = s;
    __syncthreads();
    if (threadIdx.x == 0)
        out[0] = (red[0] + red[1] + red[2] + red[3]) * (1.0f / (B * B));
}

extern "C" void kernel_launch(void* const* d_in, const int* in_sizes, int n_in,
                              void* d_out, int out_size, void* d_ws, size_t ws_size,
                              hipStream_t stream) {
    const float* z = (const float*)d_in[0];   // [128,128]
    const float* x = (const float*)d_in[1];   // [128,3,32,32]
    float* out = (float*)d_out;               // [1]
    float* ws = (float*)d_ws;

    float* zn   = ws;                         // 16384 floats
    float* zcos = ws + 16384;                 // 16384 floats
    float* maxv = ws + 32768;                 // 1 float (+63 pad)
    float* pair = ws + 32832;                 // 8256 floats (padded region 16384)
    float* xs   = ws + 32832 + 16384;         // 393216 floats

    normalize_z<<<B, D, 0, stream>>>(z, zn);
    zcos_kernel<<<B, D, 0, stream>>>(zn, zcos);
    max_kernel<<<1, 256, 0, stream>>>(zcos, maxv);
    sort_rows<<<B, 1024, 0, stream>>>(x, xs);
    pair_kernel<<<NPAIR, 64, 0, stream>>>(xs, zcos, maxv, pair);
    final_kernel<<<1, 256, 0, stream>>>(pair, out);
}

// Round 3
// 98.671 us; speedup vs baseline: 2.7377x; 1.2516x over previous
//
#include <hip/hip_runtime.h>
#include <float.h>
#include <math.h>

#define B 128
#define D 128
#define N 3072      // 3*32*32
#define NP 4096     // next pow2 for bitonic sort
#define NPAIR (B*(B+1)/2)   // 8256 upper-triangular pairs (i<=j)
#define NZBLK 16            // z-role blocks in K1 (each does 8 rows of zcos)

// ---------------------------------------------------------------------------
// K1: blocks 0..127  : bitonic-sort row b of x into xs (LDS, 1024 threads)
//     blocks 128..143: compute zcos rows 8*(b-128)..+8 with inline L2-normalize
// Fused so the tiny z pipeline rides free under the 128-CU sort phase.
// ---------------------------------------------------------------------------
__global__ __launch_bounds__(1024) void prep_kernel(const float* __restrict__ x,
                                                    const float* __restrict__ z,
                                                    float* __restrict__ xs,
                                                    float* __restrict__ zcos) {
    __shared__ float smem[NP];         // sort: 16 KB buffer; z-path: [0..127] = inv-norms
    int tid = threadIdx.x;

    if (blockIdx.x < B) {
        // ----- sort role (validated round 2, verbatim logic) -----
        float* buf = smem;
        int row = blockIdx.x;
        const float4* xr = (const float4*)(x + (size_t)row * N);
        if (tid < N / 4)
            ((float4*)buf)[tid] = xr[tid];
        else
            ((float4*)buf)[tid] = make_float4(FLT_MAX, FLT_MAX, FLT_MAX, FLT_MAX);
        __syncthreads();

        for (int k = 2; k <= NP; k <<= 1) {
            for (int j = k >> 1; j > 0; j >>= 1) {
                #pragma unroll
                for (int u = 0; u < 2; u++) {
                    int p = tid + u * 1024;        // pair index in [0, 2048)
                    int i = ((p & ~(j - 1)) << 1) | (p & (j - 1));
                    int pj = i | j;
                    float a = buf[i];
                    float b = buf[pj];
                    bool up = ((i & k) == 0);
                    if ((a > b) == up) { buf[i] = b; buf[pj] = a; }
                }
                __syncthreads();
            }
        }

        if (tid < N / 4)
            ((float4*)(xs + (size_t)row * N))[tid] = ((float4*)buf)[tid];
    } else {
        // ----- z role: 8 rows of zcos per block -----
        float* inv_s = smem;           // [128] inverse norms
        // all-row inverse norms: 8 threads per row, 16 elements each
        {
            int row = tid >> 3;        // 0..127
            int seg = tid & 7;
            const float4* zr = (const float4*)(z + row * D + seg * 16);
            float s = 0.f;
            #pragma unroll
            for (int u = 0; u < 4; u++) {
                float4 v = zr[u];
                s += v.x * v.x + v.y * v.y + v.z * v.z + v.w * v.w;
            }
            s += __shfl_down(s, 4, 8);
            s += __shfl_down(s, 2, 8);
            s += __shfl_down(s, 1, 8);
            if (seg == 0) inv_s[row] = 1.0f / fmaxf(sqrtf(s), 1e-12f);
        }
        __syncthreads();

        int gi = (blockIdx.x - B) * 8 + (tid >> 7);   // global row i
        int j  = tid & 127;
        const float4* zi = (const float4*)(z + gi * D);
        const float4* zj = (const float4*)(z + j * D);
        float dot = 0.f;
        #pragma unroll 8
        for (int k4 = 0; k4 < D / 4; k4++) {
            float4 a = zi[k4], b = zj[k4];
            dot += a.x * b.x + a.y * b.y + a.z * b.z + a.w * b.w;
        }
        zcos[gi * B + j] = dot * inv_s[gi] * inv_s[j];
    }
}

// ---------------------------------------------------------------------------
// K2: 516 blocks x 1024 threads = 16 waves/block, one upper-tri pair per wave
// (516*16 == 8256 exactly). Per-block diag-max of zcos replaces the global
// max kernel (max(z_cos) is attained on the diagonal: cos(u,v)<cos(u,u)=1).
// Block partial -> one atomicAdd into pre-zeroed d_out. EMD/cosd symmetric:
// off-diagonal pairs weighted 2x.
// ---------------------------------------------------------------------------
__global__ __launch_bounds__(1024) void pair_kernel(const float* __restrict__ xs,
                                                    const float* __restrict__ zcos,
                                                    float* __restrict__ out) {
    __shared__ float mx[2];
    __shared__ float partial[16];
    int tid = threadIdx.x;

    // diagonal max over 128 entries (2 waves)
    if (tid < B) {
        float v = zcos[tid * (B + 1)];
        #pragma unroll
        for (int o = 32; o > 0; o >>= 1) v = fmaxf(v, __shfl_down(v, o, 64));
        if ((tid & 63) == 0) mx[tid >> 6] = v;
    }
    __syncthreads();
    float maxv = fmaxf(mx[0], mx[1]);

    int w = tid >> 6;                  // wave 0..15
    int lane = tid & 63;
    int t = blockIdx.x * 16 + w;       // triangular pair index, always < NPAIR

    // decode t -> (i, j), i<=j ; start(i) = i*B - i*(i-1)/2  (validated R2)
    float ff = (float)(2 * B + 1);
    int i = (int)((ff - sqrtf(ff * ff - 8.0f * (float)t)) * 0.5f);
    if (i < 0) i = 0;
    if (i > B - 1) i = B - 1;
    while ((i + 1) * B - ((i + 1) * i) / 2 <= t) i++;
    while (i * B - (i * (i - 1)) / 2 > t) i--;
    int j = i + (t - (i * B - (i * (i - 1)) / 2));

    const float4* a = (const float4*)(xs + (size_t)i * N);
    const float4* b = (const float4*)(xs + (size_t)j * N);
    float s = 0.f;
    #pragma unroll
    for (int u = 0; u < N / 4 / 64; u++) {          // 12 iterations
        int idx = lane + u * 64;
        float4 va = a[idx], vb = b[idx];
        s += fabsf(va.x - vb.x) + fabsf(va.y - vb.y)
           + fabsf(va.z - vb.z) + fabsf(va.w - vb.w);
    }
    #pragma unroll
    for (int o = 32; o > 0; o >>= 1) s += __shfl_down(s, o, 64);
    if (lane == 0) {
        float emd = s * (1.0f / N);
        float cosd = maxv - zcos[i * B + j];
        float d = emd - cosd;
        float wgt = (i == j) ? 1.0f : 2.0f;
        partial[w] = wgt * d * d;
    }
    __syncthreads();
    if (tid == 0) {
        float blk = 0.f;
        #pragma unroll
        for (int u = 0; u < 16; u++) blk += partial[u];
        atomicAdd(out, blk * (1.0f / (B * B)));
    }
}

extern "C" void kernel_launch(void* const* d_in, const int* in_sizes, int n_in,
                              void* d_out, int out_size, void* d_ws, size_t ws_size,
                              hipStream_t stream) {
    const float* z = (const float*)d_in[0];   // [128,128]
    const float* x = (const float*)d_in[1];   // [128,3,32,32]
    float* out = (float*)d_out;               // [1]
    float* ws = (float*)d_ws;

    float* zcos = ws;                         // 16384 floats
    float* xs   = ws + 16384;                 // 393216 floats

    hipMemsetAsync(out, 0, sizeof(float), stream);   // atomicAdd target
    prep_kernel<<<B + NZBLK, 1024, 0, stream>>>(x, z, xs, zcos);
    pair_kernel<<<NPAIR / 16, 1024, 0, stream>>>(xs, zcos, out);
}